// Round 8
// baseline (571.033 us; speedup 1.0000x reference)
//
#include <hip/hip_runtime.h>
#include <cstdint>

#define T_SEQ 40
#define NB    16384
#define NH    128
#define NROWS 136          // 128 recurrent rows + 8 input rows
#define ROWD  132          // dwords/row: 528 B, 16B-aligned rows for ds_read_b128
#define WPB   16           // waves per block
#define NTHR  (WPB * 64)
#define NBLK  512          // 2 blocks/CU; each wave: lanes 0-31 = batch row A, 32-63 = row B

typedef float v4f __attribute__((ext_vector_type(4)));

// ---- per-32-lane-half sum of two floats via DPP (stays inside each half) ----
template <int C>
__device__ __forceinline__ float dppstep(float v) {
  int t = __builtin_amdgcn_update_dpp(0, __float_as_int(v), C, 0xF, 0xF, true);
  return v + __int_as_float(t);
}
__device__ __forceinline__ void half_sum2(float &a, float &b) {
  a = dppstep<0x111>(a); b = dppstep<0x111>(b);   // row_shr:1
  a = dppstep<0x112>(a); b = dppstep<0x112>(b);   // row_shr:2
  a = dppstep<0x114>(a); b = dppstep<0x114>(b);   // row_shr:4
  a = dppstep<0x118>(a); b = dppstep<0x118>(b);   // row_shr:8  -> lane15/31/47/63 row sums
  a = dppstep<0x142>(a); b = dppstep<0x142>(b);   // row_bcast15 -> lane31=sum(0..31), lane63=sum(32..63)
}
__device__ __forceinline__ float rl(float v, int l) {
  return __int_as_float(__builtin_amdgcn_readlane(__float_as_int(v), l));
}

__global__ __launch_bounds__(NTHR, 8)
void Policy_22033182228693_kernel(const float* __restrict__ x,
                                  const float* __restrict__ w_in,
                                  const float* __restrict__ w_rec,
                                  const float* __restrict__ w_out,
                                  const float* __restrict__ dmask,
                                  float* __restrict__ out)
{
  // W[j][s]: row j = pre-neuron (0..127) or input channel (128..135);
  // column slot s = 4c+p holds post-neuron h = c + 32p  (b128-contiguous per lane)
  __shared__ float W[NROWS * ROWD];   // 71,808 B -> 2 blocks/CU = 32 waves

  const int tid = threadIdx.x;
  for (int e = tid; e < NH * NH; e += NTHR) {
    int s = e >> 7, j = e & 127;                 // consecutive lanes -> consecutive j (coalesced)
    int h = (s >> 2) + ((s & 3) << 5);
    W[j * ROWD + s] = w_rec[h * NH + j];
  }
  for (int e = tid; e < NH * 8; e += NTHR) {
    int s = e >> 3, k = e & 7;
    int h = (s >> 2) + ((s & 3) << 5);
    W[(NH + k) * ROWD + s] = w_in[h * 8 + k];
  }
  __syncthreads();   // only barrier

  const int wave = tid >> 6;
  const int lane = tid & 63;
  const int half = lane >> 5;                    // 0 = batch row A, 1 = batch row B
  const int c    = lane & 31;
  const int gw   = blockIdx.x * WPB + wave;
  const int myb  = gw * 2 + half;                // this half-lane's batch row
  const float* __restrict__ Wc = W + 4 * c;      // lane's column base

  // Readout weights for neurons {c, c+32, c+64, c+96} (w_out shape (2,128))
  const float wo00 = w_out[c],        wo01 = w_out[c + 32];
  const float wo02 = w_out[c + 64],   wo03 = w_out[c + 96];
  const float wo10 = w_out[128 + c],  wo11 = w_out[160 + c];
  const float wo12 = w_out[192 + c],  wo13 = w_out[224 + c];

  // Encoder constant current: channels 0..7 live in lanes c=0..7 of each half
  float xv = x[(size_t)myb * 4 + (c & 3)];
  float cc = fmaxf(0.f, ((c & 4) ? -50.f : 50.f) * xv);
  if (c >= 8) cc = 0.f;

  // Channels with cc > 10 spike EVERY step; fold their w_in rows into a constant.
  bool always = cc > 10.f;
  uint64_t aM = __ballot((int)always);
  if (always) cc = 0.f;
  v4f cin = {0.f, 0.f, 0.f, 0.f};
  {
    uint32_t mh = (uint32_t)((half ? (aM >> 32) : aM) & 0xffu);
    while (mh) {
      int k = __builtin_ctz(mh); mh &= mh - 1;
      cin += *(const v4f*)&Wc[(NH + k) * ROWD];
    }
  }

  // Dropout mask stream: 4 b32/lane/step at {c,c+32,c+64,c+96}, 2-deep prefetch
  const float* gmu = dmask + (size_t)myb * NH;
  const size_t TS = (size_t)NB * NH;
  float mc0 = gmu[c],      mc1 = gmu[c + 32],      mc2 = gmu[c + 64],      mc3 = gmu[c + 96];
  float mn0 = gmu[TS + c], mn1 = gmu[TS + c + 32], mn2 = gmu[TS + c + 64], mn3 = gmu[TS + c + 96];

  float ve = 0.f;
  v4f v = {0.f, 0.f, 0.f, 0.f};
  v4f i = {0.f, 0.f, 0.f, 0.f};
  float ioA0 = 0.f, ioA1 = 0.f, voA0 = 0.f, voA1 = 0.f;
  float ioB0 = 0.f, ioB1 = 0.f, voB0 = 0.f, voB1 = 0.f;
  float mA0 = -3.0e38f, mA1 = -3.0e38f, mB0 = -3.0e38f, mB1 = -3.0e38f;
  uint64_t pb0 = 0, pb1 = 0, pb2 = 0, pb3 = 0;   // previous-step spike ballots

#pragma unroll 1
  for (int t = 0; t < T_SEQ; ++t) {
    // ---- encoder (slow channels only) ----
    ve += 0.1f * (cc - ve);
    bool zi = ve > 1.0f;
    if (zi) ve = 0.f;
    uint64_t bI = __ballot((int)zi);

    // ---- hidden membrane (uses old i); neuron p of lane = h = c + 32p ----
    v4f vd = v + 0.1f * (i - v);
    bool z0 = vd.x > 1.0f, z1 = vd.y > 1.0f, z2 = vd.z > 1.0f, z3 = vd.w > 1.0f;
    v.x = z0 ? 0.f : vd.x;
    v.y = z1 ? 0.f : vd.y;
    v.z = z2 ? 0.f : vd.z;
    v.w = z3 ? 0.f : vd.w;

    // ---- sparse gather: prev-step recurrent spikes + current input spikes ----
    // ballot p's half-32 bits ARE rows [32p, 32p+32): concat into 64-bit walk masks.
    v4f a = 0.8f * i;
    {
      uint32_t q0 = (uint32_t)(half ? (pb0 >> 32) : pb0);
      uint32_t q1 = (uint32_t)(half ? (pb1 >> 32) : pb1);
      uint32_t q2 = (uint32_t)(half ? (pb2 >> 32) : pb2);
      uint32_t q3 = (uint32_t)(half ? (pb3 >> 32) : pb3);
      uint64_t m01 = (uint64_t)q0 | ((uint64_t)q1 << 32);   // rows 0..63
      uint64_t m23 = (uint64_t)q2 | ((uint64_t)q3 << 32);   // rows 64..127
      uint32_t mI  = (uint32_t)((half ? (bI >> 32) : bI) & 0xffu);   // rows 128..135

      while (__any(m01 != 0)) {
        if (m01) {
          int j = __builtin_ctzll(m01); m01 &= m01 - 1;
          a += *(const v4f*)&Wc[j * ROWD];
        }
      }
      while (__any(m23 != 0)) {
        if (m23) {
          int j = __builtin_ctzll(m23); m23 &= m23 - 1;
          a += *(const v4f*)&Wc[(64 + j) * ROWD];
        }
      }
      while (__any(mI != 0)) {
        if (mI) {
          int k = __builtin_ctz(mI); mI &= mI - 1;
          a += *(const v4f*)&Wc[(NH + k) * ROWD];
        }
      }
      a += cin;
    }
    i = a;

    // ballots for next step's recurrent input
    pb0 = __ballot((int)z0);
    pb1 = __ballot((int)z1);
    pb2 = __ballot((int)z2);
    pb3 = __ballot((int)z3);

    // ---- dropout + readout ----
    float mt0 = mc0, mt1 = mc1, mt2 = mc2, mt3 = mc3;
    mc0 = mn0; mc1 = mn1; mc2 = mn2; mc3 = mn3;
    int tp = (t + 2 < T_SEQ) ? t + 2 : T_SEQ - 1;
    size_t so = (size_t)tp * TS;
    mn0 = gmu[so + c];      mn1 = gmu[so + c + 32];
    mn2 = gmu[so + c + 64]; mn3 = gmu[so + c + 96];

    float zd0 = z0 ? mt0 : 0.f, zd1 = z1 ? mt1 : 0.f;
    float zd2 = z2 ? mt2 : 0.f, zd3 = z3 ? mt3 : 0.f;
    float u0 = zd0 * wo00 + zd1 * wo01 + zd2 * wo02 + zd3 * wo03;
    float u1 = zd0 * wo10 + zd1 * wo11 + zd2 * wo12 + zd3 * wo13;

    float sA0, sA1, sB0, sB1;
    if (pb0 | pb1 | pb2 | pb3) {
      half_sum2(u0, u1);                  // lane31 = row-A sum, lane63 = row-B sum
      sA0 = rl(u0, 31); sA1 = rl(u1, 31);
      sB0 = rl(u0, 63); sB1 = rl(u1, 63);
    } else {
      sA0 = sA1 = sB0 = sB1 = 0.f;
    }

    voA0 += 0.1f * (ioA0 - voA0);  voA1 += 0.1f * (ioA1 - voA1);
    voB0 += 0.1f * (ioB0 - voB0);  voB1 += 0.1f * (ioB1 - voB1);
    ioA0 = 0.8f * ioA0 + sA0;      ioA1 = 0.8f * ioA1 + sA1;
    ioB0 = 0.8f * ioB0 + sB0;      ioB1 = 0.8f * ioB1 + sB1;
    mA0 = fmaxf(mA0, voA0);  mA1 = fmaxf(mA1, voA1);
    mB0 = fmaxf(mB0, voB0);  mB1 = fmaxf(mB1, voB1);
  }

  if (lane == 0) {
    float mxA = fmaxf(mA0, mA1);
    float eA0 = expf(mA0 - mxA), eA1 = expf(mA1 - mxA);
    float invA = 1.f / (eA0 + eA1);
    float mxB = fmaxf(mB0, mB1);
    float eB0 = expf(mB0 - mxB), eB1 = expf(mB1 - mxB);
    float invB = 1.f / (eB0 + eB1);
    ((float4*)out)[gw] = make_float4(eA0 * invA, eA1 * invA, eB0 * invB, eB1 * invB);
  }
}

extern "C" void kernel_launch(void* const* d_in, const int* in_sizes, int n_in,
                              void* d_out, int out_size, void* d_ws, size_t ws_size,
                              hipStream_t stream) {
  const float* x     = (const float*)d_in[0];
  const float* w_in  = (const float*)d_in[1];
  const float* w_rec = (const float*)d_in[2];
  const float* w_out = (const float*)d_in[3];
  const float* dmask = (const float*)d_in[4];
  float* out = (float*)d_out;

  hipLaunchKernelGGL(Policy_22033182228693_kernel, dim3(NBLK), dim3(NTHR), 0, stream,
                     x, w_in, w_rec, w_out, dmask, out);
}

// Round 9
// 460.667 us; speedup vs baseline: 1.2396x; 1.2396x over previous
//
#include <hip/hip_runtime.h>
#include <cstdint>

#define T_SEQ 40
#define NB    16384
#define NH    128
#define ZSTR  168            // bf16 elems per z-tile row (160 used; 336 B stride spreads banks)
#define GROWS 16             // batch rows per block
#define NTHR  256            // 4 waves; wave w owns neuron cols [32w, 32w+32)
#define NBLK  (NB / GROWS)   // 1024 blocks

typedef float v4f __attribute__((ext_vector_type(4)));
typedef short v8s __attribute__((ext_vector_type(8)));

// RNE float->bf16 bits; w == b1+b2+b3 exactly (24-bit mantissa = 3x8)
__device__ __forceinline__ unsigned short f2bf(float f) {
  uint32_t u = __float_as_uint(f);
  return (unsigned short)((u + 0x7FFFu + ((u >> 16) & 1u)) >> 16);
}
__device__ __forceinline__ float bf2f(unsigned short b) {
  return __uint_as_float(((uint32_t)b) << 16);
}
template <int C>
__device__ __forceinline__ float dppadd(float v) {
  int t = __builtin_amdgcn_update_dpp(0, __float_as_int(v), C, 0xF, 0xF, true);
  return v + __int_as_float(t);
}
__device__ __forceinline__ float red16(float v) {   // sum over each 16-lane DPP row
  v = dppadd<0x111>(v);
  v = dppadd<0x112>(v);
  v = dppadd<0x114>(v);
  v = dppadd<0x118>(v);
  return v;                                          // lane q*16+15 holds the sum
}

__global__ __launch_bounds__(NTHR, 2)
void Policy_22033182228693_kernel(const float* __restrict__ x,
                                  const float* __restrict__ w_in,
                                  const float* __restrict__ w_rec,
                                  const float* __restrict__ w_out,
                                  const float* __restrict__ dmask,
                                  float* __restrict__ out)
{
  __shared__ unsigned short Z[2][GROWS * ZSTR];   // [z(128) | xs(8) | pad0(24..32)] bf16, dbuf
  __shared__ unsigned short XS[T_SEQ * 128];      // precomputed encoder spikes, [t][batch*8+ch]
  __shared__ float UP[2][4][GROWS][2];            // per-wave readout partials, dbuf
  __shared__ float MF[GROWS][2];

  const int tid  = threadIdx.x;
  const int wv   = tid >> 6;
  const int lane = tid & 63;
  const int m    = lane & 15;     // MFMA 16-index (A row / B col / C col)
  const int q    = lane >> 4;     // quad
  const int wcol = wv * 32;
  const int gb   = blockIdx.x * GROWS;

  // ---- stage register-resident B-frags: B[k][n] = W[n][k], 3-way exact bf16 split ----
  // assumed B lane map (mirror of verified A map): n = lane&15, k = quad*8 + j
  v8s bfr[2][5][3];
#pragma unroll
  for (int tau = 0; tau < 2; ++tau) {
    const int n = wcol + tau * 16 + m;
#pragma unroll
    for (int c = 0; c < 5; ++c) {
      const int kb = c * 32 + q * 8;
      union { v8s v; unsigned short u[8]; } f0, f1, f2;
#pragma unroll
      for (int j = 0; j < 8; ++j) {
        const int k = kb + j;
        float w = (k < NH)  ? w_rec[n * NH + k]
                : (k < 136) ? w_in[n * 8 + (k - NH)] : 0.f;
        unsigned short b1 = f2bf(w);  float r1 = w - bf2f(b1);
        unsigned short b2 = f2bf(r1); float r2 = r1 - bf2f(b2);
        unsigned short b3 = f2bf(r2);
        f0.u[j] = b1; f1.u[j] = b2; f2.u[j] = b3;
      }
      bfr[tau][c][0] = f0.v; bfr[tau][c][1] = f1.v; bfr[tau][c][2] = f2.v;
    }
  }

  // readout weights for this lane's two columns
  const float wo00 = w_out[wcol + m],      wo01 = w_out[wcol + 16 + m];
  const float wo10 = w_out[NH + wcol + m], wo11 = w_out[NH + wcol + 16 + m];

  // zero both z-tile buffers (incl. pad cols) once
  for (int e = tid; e < 2 * GROWS * ZSTR; e += NTHR) ((unsigned short*)Z)[e] = 0;
  __syncthreads();

  // ---- encoder precompute: (batch,channel) pairs on threads 0..127 ----
  if (tid < 128) {
    const int bi = tid >> 3, ch = tid & 7;
    float xv = x[(size_t)(gb + bi) * 4 + (ch & 3)];
    float cc = fmaxf(0.f, ((ch & 4) ? -50.f : 50.f) * xv);
    float ve = 0.f;
    for (int t = 0; t < T_SEQ; ++t) {
      ve += 0.1f * (cc - ve);
      unsigned short zb = 0;
      if (ve > 1.0f) { zb = 0x3F80; ve = 0.f; }
      XS[t * 128 + tid] = zb;
      if (t == 0) Z[0][bi * ZSTR + NH + ch] = zb;   // xs[0] into buffer 0
    }
  }
  __syncthreads();

  v4f iacc[2] = {{0,0,0,0},{0,0,0,0}};
  v4f vmem[2] = {{0,0,0,0},{0,0,0,0}};
  float io = 0.f, vo = 0.f, mx = -3.0e38f;          // wave-0 lanes 0..31: (row=lane>>1, out=lane&1)
  const size_t TS = (size_t)NB * NH;
  int pb = 0;

#pragma unroll 1
  for (int t = 0; t < T_SEQ; ++t) {
    // dropout mask for this step (issued early; consumed after MFMA section)
    float mk[2][4];
#pragma unroll
    for (int tau = 0; tau < 2; ++tau)
#pragma unroll
      for (int r = 0; r < 4; ++r)
        mk[tau][r] = dmask[(size_t)t * TS + (size_t)(gb + q * 4 + r) * NH + wcol + tau * 16 + m];

    // A-frags from Z[pb]: A[m][k], k = c*32 + q*8 + j  (b128 reads)
    v8s af[5];
    const unsigned short* zrow = &Z[pb][m * ZSTR];
#pragma unroll
    for (int c = 0; c < 5; ++c) af[c] = *(const v8s*)(zrow + c * 32 + q * 8);

    // membrane from OLD i (C-layout: row = q*4+r, col = wcol + tau*16 + m)
    float zf[2][4];
#pragma unroll
    for (int tau = 0; tau < 2; ++tau) {
      v4f vd = vmem[tau] + 0.1f * (iacc[tau] - vmem[tau]);
#pragma unroll
      for (int r = 0; r < 4; ++r) {
        bool z = vd[r] > 1.0f;
        zf[tau][r] = z ? 1.0f : 0.0f;
        vmem[tau][r] = z ? 0.0f : vd[r];
      }
    }

    // i_new = 0.8*i_old + [z_old | xs_t] @ W^T   (3 exact bf16 splits, fp32 acc)
    v4f a0 = 0.8f * iacc[0];
    v4f a1 = 0.8f * iacc[1];
#pragma unroll
    for (int s = 0; s < 3; ++s)
#pragma unroll
      for (int c = 0; c < 5; ++c) {
        a0 = __builtin_amdgcn_mfma_f32_16x16x32_bf16(af[c], bfr[0][c][s], a0, 0, 0, 0);
        a1 = __builtin_amdgcn_mfma_f32_16x16x32_bf16(af[c], bfr[1][c][s], a1, 0, 0, 0);
      }
    iacc[0] = a0; iacc[1] = a1;

    // write z_new (bf16 0/1) into the other buffer
    unsigned short* zq = &Z[pb ^ 1][0];
#pragma unroll
    for (int tau = 0; tau < 2; ++tau)
#pragma unroll
      for (int r = 0; r < 4; ++r)
        zq[(q * 4 + r) * ZSTR + wcol + tau * 16 + m] = (zf[tau][r] != 0.f) ? 0x3F80 : 0;

    // xs[t+1] into the other buffer (threads 128..255)
    if (t + 1 < T_SEQ && tid >= 128) {
      const int u = tid - 128;
      Z[pb ^ 1][(u >> 3) * ZSTR + NH + (u & 7)] = XS[(t + 1) * 128 + u];
    }

    // readout partials: u[b][o] contributions over this wave's 32 cols
#pragma unroll
    for (int r = 0; r < 4; ++r) {
      float zd0 = zf[0][r] * mk[0][r];
      float zd1 = zf[1][r] * mk[1][r];
      float p0 = zd0 * wo00 + zd1 * wo01;
      float p1 = zd0 * wo10 + zd1 * wo11;
      p0 = red16(p0);
      p1 = red16(p1);
      if (m == 15) {
        UP[t & 1][wv][q * 4 + r][0] = p0;
        UP[t & 1][wv][q * 4 + r][1] = p1;
      }
    }

    __syncthreads();   // z-tile + partials complete

    // wave 0: LI readout state update for all 16 batch rows
    if (wv == 0 && lane < 32) {
      const int row = lane >> 1, o = lane & 1;
      float u = UP[t & 1][0][row][o] + UP[t & 1][1][row][o]
              + UP[t & 1][2][row][o] + UP[t & 1][3][row][o];
      float von = vo + 0.1f * (io - vo);   // uses old io
      io = 0.8f * io + u;
      vo = von;
      mx = fmaxf(mx, vo);
    }
    pb ^= 1;
  }

  __syncthreads();
  if (wv == 0 && lane < 32) MF[lane >> 1][lane & 1] = mx;
  __syncthreads();
  if (tid < GROWS) {
    float a = MF[tid][0], b = MF[tid][1];
    float mxx = fmaxf(a, b);
    float e0 = expf(a - mxx), e1 = expf(b - mxx);
    float inv = 1.f / (e0 + e1);
    ((float2*)out)[gb + tid] = make_float2(e0 * inv, e1 * inv);
  }
}

extern "C" void kernel_launch(void* const* d_in, const int* in_sizes, int n_in,
                              void* d_out, int out_size, void* d_ws, size_t ws_size,
                              hipStream_t stream) {
  const float* x     = (const float*)d_in[0];
  const float* w_in  = (const float*)d_in[1];
  const float* w_rec = (const float*)d_in[2];
  const float* w_out = (const float*)d_in[3];
  const float* dmask = (const float*)d_in[4];
  float* out = (float*)d_out;

  hipLaunchKernelGGL(Policy_22033182228693_kernel, dim3(NBLK), dim3(NTHR), 0, stream,
                     x, w_in, w_rec, w_out, dmask, out);
}